// Round 13
// baseline (230.885 us; speedup 1.0000x reference)
//
#include <hip/hip_runtime.h>
#include <stdint.h>

#define SIZE 65535

typedef __bf16 bf16x8 __attribute__((ext_vector_type(8)));
typedef float floatx4 __attribute__((ext_vector_type(4)));

// ws layout (bf16 elements), FRAGMENT-LINEAR: chunk = tile*64 + lane, 8 elems/chunk.
#define WS_ENCW 0        // [nt8][kt8][lane][8]        -> 32768
#define WS_WIH  32768    // [nt8][g3][kt4][lane][8]    -> 49152
#define WS_WHH  81920    // [nt8][g3][kt4][lane][8]    -> 49152
#define WS_VW   131072   // [nt4][kt4][lane][8]        -> 8192
#define WS_DECW 139264   // [kt6][lane][8] (rows>=10 zero) -> 3072
#define WS_TOTC 17792    // total chunks (x64x8 elems = 142336)

__device__ __forceinline__ unsigned short f2bf(float f) {
    union { float f; unsigned int u; } v; v.f = f;
    unsigned int u = v.u;
    return (unsigned short)((u + 0x7fffu + ((u >> 16) & 1u)) >> 16);
}
// native cast -> hardware cvt (RNE, same rounding as manual)
__device__ __forceinline__ unsigned short f2bfn(float f) {
    union { __bf16 h; unsigned short s; } u; u.h = (__bf16)f;
    return u.s;
}
__device__ __forceinline__ float bf2f(unsigned short b) {
    union { unsigned int u; float f; } v; v.u = ((unsigned int)b) << 16;
    return v.f;
}
__device__ __forceinline__ float sigmf(float x) {
    x = fminf(fmaxf(x, -30.f), 30.f);
    return 1.f / (1.f + __expf(-x));
}
__device__ __forceinline__ float tanhfast(float x) {
    x = fminf(fmaxf(x, -15.f), 15.f);
    float e = __expf(2.f * x);
    return (e - 1.f) / (e + 1.f);
}

__device__ __forceinline__ bf16x8 cvt8g(const float* p) {
    float4 a = *reinterpret_cast<const float4*>(p);
    float4 b = *reinterpret_cast<const float4*>(p + 4);
    bf16x8 r;
    r[0] = (__bf16)a.x; r[1] = (__bf16)a.y; r[2] = (__bf16)a.z; r[3] = (__bf16)a.w;
    r[4] = (__bf16)b.x; r[5] = (__bf16)b.y; r[6] = (__bf16)b.z; r[7] = (__bf16)b.w;
    return r;
}
__device__ __forceinline__ bf16x8 ld8(const unsigned short* p) {
    return *reinterpret_cast<const bf16x8*>(p);
}

// async global->LDS, 16B per lane, no VGPR destination; counted by vmcnt.
__device__ __forceinline__ void glds16(const unsigned short* g, unsigned short* l) {
    __builtin_amdgcn_global_load_lds(
        (const __attribute__((address_space(1))) unsigned int*)g,
        (__attribute__((address_space(3))) unsigned int*)l, 16, 0, 0);
}

#define WAITVM(N) asm volatile("s_waitcnt vmcnt(" #N ")" ::: "memory")
#define SFENCE()  __builtin_amdgcn_sched_barrier(0)
// R12 BUGFIX: ds_read completion fence before restaging the just-read slot.
// global_load_lds LDS-writes return via TA/TD, NOT the wave's DS queue — a
// pending ds_read has NO ordering vs the returning write. lgkmcnt(0) forces
// the reads into VGPRs before the slot is reused; sched_barrier pins it
// (rule #18: compiler may hoist reg-only MFMA past inline-asm lgkmcnt).
#define WAITLGKM0() do { asm volatile("s_waitcnt lgkmcnt(0)" ::: "memory"); \
                         __builtin_amdgcn_sched_barrier(0); } while (0)

// ---- wave-private stage helpers: EXACT VMEM-op counts are load-bearing ----
// stage_enc / stage_gruW / stage_vW = 8 glds16; stage_decW = 6 glds16.
__device__ __forceinline__ void stage_enc(unsigned short* dst, const unsigned short* wsw,
                                          int nt, int lane) {
#pragma unroll
    for (int f = 0; f < 8; ++f)
        glds16(wsw + WS_ENCW + (size_t)(nt * 8 + f) * 512 + lane * 8, dst + f * 512);
}
__device__ __forceinline__ void stage_gruW(unsigned short* dst, const unsigned short* wsw,
                                           int ng, int lane) {
#pragma unroll
    for (int f = 0; f < 4; ++f) {
        glds16(wsw + WS_WIH + (size_t)(ng * 4 + f) * 512 + lane * 8, dst + f * 512);
        glds16(wsw + WS_WHH + (size_t)(ng * 4 + f) * 512 + lane * 8, dst + (4 + f) * 512);
    }
}
__device__ __forceinline__ void stage_vW(unsigned short* dst, const unsigned short* wsw,
                                         int half, int lane) {
#pragma unroll
    for (int f = 0; f < 8; ++f)
        glds16(wsw + WS_VW + (size_t)(half * 8 + f) * 512 + lane * 8, dst + f * 512);
}
__device__ __forceinline__ void stage_decW(unsigned short* dst, const unsigned short* wsw,
                                           int lane) {
#pragma unroll
    for (int f = 0; f < 6; ++f)
        glds16(wsw + WS_DECW + (size_t)f * 512 + lane * 8, dst + f * 512);
}

// ---------- pre-kernel: f32 weights -> bf16 fragment-linear layout ----------
__global__ __launch_bounds__(256) void cvt_weights(
    const float* __restrict__ enc_w, const float* __restrict__ w_ih,
    const float* __restrict__ w_hh, const float* __restrict__ v_w,
    const float* __restrict__ dec_w, unsigned short* __restrict__ ws) {
    int c = blockIdx.x * 256 + threadIdx.x;
    if (c >= WS_TOTC) return;
    const int lane = c & 63;
    const int l = lane & 15;
    const int q = lane >> 4;
    const float* src; int row, col, stride; bool zero = false;
    if (c < 4096) {                      // enc_w [nt8][kt8]
        int lt = c >> 6; int nt = lt >> 3, kt = lt & 7;
        row = nt * 16 + l; col = kt * 32 + q * 8; src = enc_w; stride = 256;
    } else if (c < 10240) {              // w_ih [nt8][g3][kt4]
        int lt = (c - 4096) >> 6; int nt = lt / 12; int r2 = lt % 12;
        int g = r2 >> 2, kt = r2 & 3;
        row = g * 128 + nt * 16 + l; col = kt * 32 + q * 8; src = w_ih; stride = 128;
    } else if (c < 16384) {              // w_hh
        int lt = (c - 10240) >> 6; int nt = lt / 12; int r2 = lt % 12;
        int g = r2 >> 2, kt = r2 & 3;
        row = g * 128 + nt * 16 + l; col = kt * 32 + q * 8; src = w_hh; stride = 128;
    } else if (c < 17408) {              // v_w [nt4][kt4]
        int lt = (c - 16384) >> 6; int nt = lt >> 2, kt = lt & 3;
        row = nt * 16 + l; col = kt * 32 + q * 8; src = v_w; stride = 128;
    } else {                             // dec_w [kt6], zero-pad rows 10..15
        int kt = (c - 17408) >> 6;
        row = l; col = kt * 32 + q * 8; src = dec_w; stride = 192;
        zero = (l >= 10);
    }
    float4 a, b;
    if (zero) { a = make_float4(0.f,0.f,0.f,0.f); b = a; }
    else {
        const float* p = src + (size_t)row * stride + col;
        a = *reinterpret_cast<const float4*>(p);
        b = *reinterpret_cast<const float4*>(p + 4);
    }
    unsigned short* d = ws + (size_t)c * 8;
    d[0]=f2bf(a.x); d[1]=f2bf(a.y); d[2]=f2bf(a.z); d[3]=f2bf(a.w);
    d[4]=f2bf(b.x); d[5]=f2bf(b.y); d[6]=f2bf(b.z); d[7]=f2bf(b.w);
}

// ---------- main fused kernel: WAVE-PRIVATE DRAIN-FREE STREAMING (fixed) ----------
// R12 + the WAITLGKM0 read-completion fence before every same-slot restage.
// Still: ZERO barriers after prologue, ZERO vmcnt(0) until the tail; 3-slot
// x 8KB wave-private ring, 3 chunks in flight; exact counted vmcnt
// (phase1 16 = {c+1,c+2}; phase2 24 = {c+1,c+2,hp(8)}; tail 14/6/0).
// Biases in LDS (no stray VMEM in the counted stream). sA/sV/sO wave-private.
// LDS 157KB -> 1 block/CU (occupancy proven irrelevant across R1/R10).
__global__ __launch_bounds__(256) void attn_critic_kernel(
    const float* __restrict__ obs,    // [SIZE,256] f32
    const float* __restrict__ hid,    // [SIZE,128] f32
    const float* __restrict__ enc_b,  // [128] f32
    const float* __restrict__ b_ih,   // [384] f32
    const float* __restrict__ b_hh,   // [384] f32
    const float* __restrict__ v_b,    // [64] f32
    const float* __restrict__ dec_b,  // [10] f32
    const unsigned short* __restrict__ wsw,  // bf16 fragment-linear weights
    float* __restrict__ out)          // [SIZE*10] ++ [SIZE*128] f32
{
    __shared__ __align__(16) unsigned short wring[4][12288];  // 3 slots x 8KB per wave
    __shared__ __align__(16) unsigned short sA[4][32][136];   // x then h_out
    __shared__ __align__(16) unsigned short sV[4][32][72];    // v
    __shared__ __align__(16) float sO[4][32][10];             // logits
    // [0..127]=enc_b [128..511]=b_ih [512..895]=b_hh [896..959]=v_b [960..969]=dec_b
    __shared__ __align__(16) float sBias[976];

    const int tid  = threadIdx.x;
    const int wave = tid >> 6;
    const int lane = tid & 63;
    const int l15  = lane & 15;
    const int quad = lane >> 4;
    const int wrow0 = (blockIdx.x * 4 + wave) * 32;

    unsigned short* const ring = &wring[wave][0];

    int rA0 = wrow0 + l15;      rA0 = (rA0 < SIZE) ? rA0 : (SIZE - 1);
    int rA1 = wrow0 + 16 + l15; rA1 = (rA1 < SIZE) ? rA1 : (SIZE - 1);

    // ---- prologue: stage chunks c0..c2 (enc nt0..2), biases->LDS, prefetch ----
    stage_enc(ring + 0 * 4096, wsw, 0, lane);
    stage_enc(ring + 1 * 4096, wsw, 1, lane);
    stage_enc(ring + 2 * 4096, wsw, 2, lane);

    for (int i = tid; i < 970; i += 256) {
        float v;
        if (i < 128)      v = enc_b[i];
        else if (i < 512) v = b_ih[i - 128];
        else if (i < 896) v = b_hh[i - 512];
        else if (i < 960) v = v_b[i - 896];
        else              v = dec_b[i - 960];
        sBias[i] = v;
    }

    bf16x8 aob[2][8], hf[2][4];
    {
        const float* o0 = obs + (size_t)rA0 * 256;
        const float* o1 = obs + (size_t)rA1 * 256;
#pragma unroll
        for (int kt = 0; kt < 8; ++kt) {
            aob[0][kt] = cvt8g(o0 + kt * 32 + quad * 8);
            aob[1][kt] = cvt8g(o1 + kt * 32 + quad * 8);
        }
        const float* h0 = hid + (size_t)rA0 * 128;
        const float* h1 = hid + (size_t)rA1 * 128;
#pragma unroll
        for (int kt = 0; kt < 4; ++kt) {
            hf[0][kt] = cvt8g(h0 + kt * 32 + quad * 8);
            hf[1][kt] = cvt8g(h1 + kt * 32 + quad * 8);
        }
    }
    SFENCE();
    __syncthreads();   // sBias visible; drains prologue vmcnt (c0..c2 valid)

    // ============ from here on: NO barriers, NO vmcnt(0) until tail ============

    // ---- Phase 1: X = relu(OBS @ enc_w^T + enc_b); chunks c0..c7 ----
#pragma unroll 1
    for (int nt = 0; nt < 8; ++nt) {
        unsigned short* slotp = ring + (nt % 3) * 4096;
        WAITVM(16);
        bf16x8 bw[8];
#pragma unroll
        for (int kt = 0; kt < 8; ++kt)
            bw[kt] = ld8(slotp + kt * 512 + lane * 8);
        WAITLGKM0();   // reads in VGPRs before the slot is reused (R12 fix)
        if (nt < 5) stage_enc(slotp, wsw, nt + 3, lane);
        else        stage_gruW(slotp, wsw, nt - 5, lane);
        floatx4 a0 = floatx4{0.f,0.f,0.f,0.f}, a1 = a0;
#pragma unroll
        for (int kt = 0; kt < 8; ++kt) {
            a0 = __builtin_amdgcn_mfma_f32_16x16x32_bf16(aob[0][kt], bw[kt], a0, 0, 0, 0);
            a1 = __builtin_amdgcn_mfma_f32_16x16x32_bf16(aob[1][kt], bw[kt], a1, 0, 0, 0);
        }
        const float bias = sBias[nt * 16 + l15];
#pragma unroll
        for (int r = 0; r < 4; ++r) {
            sA[wave][quad * 4 + r][nt * 16 + l15]      = f2bfn(fmaxf(a0[r] + bias, 0.f));
            sA[wave][16 + quad * 4 + r][nt * 16 + l15] = f2bfn(fmaxf(a1[r] + bias, 0.f));
        }
    }

    bf16x8 xf[2][4];
#pragma unroll
    for (int kt = 0; kt < 4; ++kt) {
        xf[0][kt] = ld8(&sA[wave][l15][kt * 32 + quad * 8]);
        xf[1][kt] = ld8(&sA[wave][16 + l15][kt * 32 + quad * 8]);
    }

    // ---- Phase 2: GRU cell; chunks c8..c31 (c = 8+3nt+g) ----
#pragma unroll 1
    for (int nt = 0; nt < 8; ++nt) {
        const int nr = nt * 16 + l15;
        float hp[2][4];
#pragma unroll
        for (int m = 0; m < 2; ++m)
#pragma unroll
            for (int r = 0; r < 4; ++r) {
                const int grow = wrow0 + m * 16 + quad * 4 + r;
                const int rowc = (grow < SIZE) ? grow : (SIZE - 1);
                hp[m][r] = hid[(size_t)rowc * 128 + nr];
            }
        const float bir_ = sBias[128 + nr], biz_ = sBias[256 + nr], bin_ = sBias[384 + nr];
        const float bhr_ = sBias[512 + nr], bhz_ = sBias[640 + nr], bhn_ = sBias[768 + nr];
        floatx4 gi[3][2], gh[3][2];
#pragma unroll
        for (int g = 0; g < 3; ++g) {
            gi[g][0] = floatx4{0.f,0.f,0.f,0.f}; gi[g][1] = gi[g][0];
            gh[g][0] = gi[g][0]; gh[g][1] = gi[g][0];
        }
#pragma unroll
        for (int g = 0; g < 3; ++g) {
            unsigned short* slotp = ring + ((2 + g) % 3) * 4096;
            WAITVM(24);
            bf16x8 bi[4], bh[4];
#pragma unroll
            for (int kt = 0; kt < 4; ++kt) {
                bi[kt] = ld8(slotp + kt * 512 + lane * 8);
                bh[kt] = ld8(slotp + (4 + kt) * 512 + lane * 8);
            }
            WAITLGKM0();   // reads in VGPRs before the slot is reused (R12 fix)
            const int tgt = 11 + 3 * nt + g;         // chunk c+3 (wave-uniform)
            if (tgt <= 31)      stage_gruW(slotp, wsw, tgt - 8, lane);
            else if (tgt == 32) stage_vW(slotp, wsw, 0, lane);
            else if (tgt == 33) stage_vW(slotp, wsw, 1, lane);
            else                stage_decW(slotp, wsw, lane);
#pragma unroll
            for (int kt = 0; kt < 4; ++kt) {
                gi[g][0] = __builtin_amdgcn_mfma_f32_16x16x32_bf16(xf[0][kt], bi[kt], gi[g][0], 0, 0, 0);
                gi[g][1] = __builtin_amdgcn_mfma_f32_16x16x32_bf16(xf[1][kt], bi[kt], gi[g][1], 0, 0, 0);
                gh[g][0] = __builtin_amdgcn_mfma_f32_16x16x32_bf16(hf[0][kt], bh[kt], gh[g][0], 0, 0, 0);
                gh[g][1] = __builtin_amdgcn_mfma_f32_16x16x32_bf16(hf[1][kt], bh[kt], gh[g][1], 0, 0, 0);
            }
        }
#pragma unroll
        for (int m = 0; m < 2; ++m)
#pragma unroll
            for (int r = 0; r < 4; ++r) {
                float rg = sigmf(gi[0][m][r] + bir_ + gh[0][m][r] + bhr_);
                float zg = sigmf(gi[1][m][r] + biz_ + gh[1][m][r] + bhz_);
                float ng2 = tanhfast(gi[2][m][r] + bin_ + rg * (gh[2][m][r] + bhn_));
                float ho = (1.f - zg) * ng2 + zg * hp[m][r];
                sA[wave][m * 16 + quad * 4 + r][nr] = f2bfn(ho);
            }
    }

    // ---- Phase 3: V = relu(H_OUT @ v_w^T + v_b); c32 (slot2), c33 (slot0) ----
    bf16x8 af[2][4];
#pragma unroll
    for (int kt = 0; kt < 4; ++kt) {
        af[0][kt] = ld8(&sA[wave][l15][kt * 32 + quad * 8]);
        af[1][kt] = ld8(&sA[wave][16 + l15][kt * 32 + quad * 8]);
    }
    WAITVM(14);   // c32 ready (younger: c33=8, c34=6)
#pragma unroll
    for (int nt = 0; nt < 2; ++nt) {
        const unsigned short* slotp = ring + 2 * 4096;
        const float bias = sBias[896 + nt * 16 + l15];
        floatx4 a0 = floatx4{0.f,0.f,0.f,0.f}, a1 = a0;
#pragma unroll
        for (int kt = 0; kt < 4; ++kt) {
            bf16x8 b = ld8(slotp + (nt * 4 + kt) * 512 + lane * 8);
            a0 = __builtin_amdgcn_mfma_f32_16x16x32_bf16(af[0][kt], b, a0, 0, 0, 0);
            a1 = __builtin_amdgcn_mfma_f32_16x16x32_bf16(af[1][kt], b, a1, 0, 0, 0);
        }
#pragma unroll
        for (int r = 0; r < 4; ++r) {
            sV[wave][quad * 4 + r][nt * 16 + l15]      = f2bfn(fmaxf(a0[r] + bias, 0.f));
            sV[wave][16 + quad * 4 + r][nt * 16 + l15] = f2bfn(fmaxf(a1[r] + bias, 0.f));
        }
    }
    WAITVM(6);    // c33 ready (younger: c34=6)
#pragma unroll
    for (int nt = 2; nt < 4; ++nt) {
        const unsigned short* slotp = ring + 0 * 4096;
        const float bias = sBias[896 + nt * 16 + l15];
        floatx4 a0 = floatx4{0.f,0.f,0.f,0.f}, a1 = a0;
#pragma unroll
        for (int kt = 0; kt < 4; ++kt) {
            bf16x8 b = ld8(slotp + ((nt - 2) * 4 + kt) * 512 + lane * 8);
            a0 = __builtin_amdgcn_mfma_f32_16x16x32_bf16(af[0][kt], b, a0, 0, 0, 0);
            a1 = __builtin_amdgcn_mfma_f32_16x16x32_bf16(af[1][kt], b, a1, 0, 0, 0);
        }
#pragma unroll
        for (int r = 0; r < 4; ++r) {
            sV[wave][quad * 4 + r][nt * 16 + l15]      = f2bfn(fmaxf(a0[r] + bias, 0.f));
            sV[wave][16 + quad * 4 + r][nt * 16 + l15] = f2bfn(fmaxf(a1[r] + bias, 0.f));
        }
    }

    // ---- Phase 4: OUT = [H_OUT|V] @ dec_w^T + dec_b; c34 (slot1) ----
    {
        WAITVM(0);   // dec staged; the kernel's only full drain
        const unsigned short* slotp = ring + 1 * 4096;
        floatx4 d0 = floatx4{0.f,0.f,0.f,0.f}, d1 = d0;
#pragma unroll
        for (int kt = 0; kt < 6; ++kt) {
            bf16x8 b = ld8(slotp + kt * 512 + lane * 8);
            bf16x8 a0 = (kt < 4) ? af[0][kt] : ld8(&sV[wave][l15][(kt - 4) * 32 + quad * 8]);
            bf16x8 a1 = (kt < 4) ? af[1][kt] : ld8(&sV[wave][16 + l15][(kt - 4) * 32 + quad * 8]);
            d0 = __builtin_amdgcn_mfma_f32_16x16x32_bf16(a0, b, d0, 0, 0, 0);
            d1 = __builtin_amdgcn_mfma_f32_16x16x32_bf16(a1, b, d1, 0, 0, 0);
        }
        if (l15 < 10) {
            const float bias = sBias[960 + l15];
#pragma unroll
            for (int r = 0; r < 4; ++r) {
                sO[wave][quad * 4 + r][l15]      = d0[r] + bias;
                sO[wave][16 + quad * 4 + r][l15] = d1[r] + bias;
            }
        }
        // coalesced store: 320 consecutive f32 per wave
#pragma unroll
        for (int j = 0; j < 5; ++j) {
            int idx = j * 64 + lane;          // 0..319
            int row = idx / 10, col = idx % 10;
            int grow = wrow0 + row;
            if (grow < SIZE)
                out[(size_t)grow * 10 + col] = sO[wave][row][col];
        }
    }

    // ---- h_out -> global, coalesced full lines (from sA) ----
    {
        float* out_h = out + (size_t)SIZE * 10;
#pragma unroll 1
        for (int it = 0; it < 16; ++it) {
            int idx = it * 256 + lane * 4;   // over [32][128]
            int rr = idx >> 7, cc = idx & 127;
            int grow = wrow0 + rr;
            if (grow < SIZE) {
                float2 p0 = make_float2(bf2f(sA[wave][rr][cc]),     bf2f(sA[wave][rr][cc + 1]));
                float2 p1 = make_float2(bf2f(sA[wave][rr][cc + 2]), bf2f(sA[wave][rr][cc + 3]));
                float* dst = out_h + (size_t)grow * 128 + cc;
                *reinterpret_cast<float2*>(dst)     = p0;
                *reinterpret_cast<float2*>(dst + 2) = p1;
            }
        }
    }
}

extern "C" void kernel_launch(void* const* d_in, const int* in_sizes, int n_in,
                              void* d_out, int out_size, void* d_ws, size_t ws_size,
                              hipStream_t stream) {
    const float* obs   = (const float*)d_in[0];
    const float* hid   = (const float*)d_in[1];
    const float* enc_w = (const float*)d_in[2];
    const float* enc_b = (const float*)d_in[3];
    const float* w_ih  = (const float*)d_in[4];
    const float* w_hh  = (const float*)d_in[5];
    const float* b_ih  = (const float*)d_in[6];
    const float* b_hh  = (const float*)d_in[7];
    // d_in[8..19]: dead code (bi-GRU / hard attention / q,k) — unused.
    const float* v_w   = (const float*)d_in[20];
    const float* v_b   = (const float*)d_in[21];
    const float* dec_w = (const float*)d_in[22];
    const float* dec_b = (const float*)d_in[23];
    unsigned short* wsw = (unsigned short*)d_ws;
    float* out = (float*)d_out;

    hipLaunchKernelGGL(cvt_weights, dim3((WS_TOTC + 255) / 256), dim3(256), 0, stream,
                       enc_w, w_ih, w_hh, v_w, dec_w, wsw);
    // 512 blocks x 4 waves x 32 rows = 65536 >= 65535; 1 block/CU (LDS 157KB)
    hipLaunchKernelGGL(attn_critic_kernel, dim3(512), dim3(256), 0, stream,
                       obs, hid, enc_b, b_ih, b_hh, v_b, dec_b, wsw, out);
}